// Round 1
// baseline (83.560 us; speedup 1.0000x reference)
//
#include <hip/hip_runtime.h>

// Sliding-window min, window=64, over rows of T=8192 fp32.
// y[b,t] = min over k in [t-63, t] of (k>=0 ? x[b,k] : 9999).
//
// Wave-aligned Gil-Werman: segments of 64 = one wave. Per segment compute
// prefix-min P (shfl_up scan) and suffix-min S (shfl_down scan); then
// y[lane] = min(P[lane], S_prev[lane+1]) where S_prev is the previous
// segment's suffix-min, carried in registers across the wave's 32 segments.

constexpr int T = 8192;
constexpr float INIT_VAL = 9999.0f;
constexpr int WAVE = 64;
constexpr int WAVES_PER_BLOCK = 4;
constexpr int SEGS_PER_WAVE = T / (WAVE * WAVES_PER_BLOCK); // 32

__global__ __launch_bounds__(WAVE * WAVES_PER_BLOCK)
void tlalw_kernel(const float* __restrict__ x, float* __restrict__ y) {
    const int lane = threadIdx.x & (WAVE - 1);
    const int wv = threadIdx.x >> 6;
    const long long rowBase = (long long)blockIdx.x * T;
    const int tbase = wv * (SEGS_PER_WAVE * WAVE);

    const float* __restrict__ xr = x + rowBase;
    float* __restrict__ yr = y + rowBase;

    // prevShift[lane] = suffix-min of previous segment starting at lane+1
    // (lane 63's window lies entirely in the current segment -> INIT_VAL,
    // which matches the reference's 9999 padding semantics exactly).
    float prevShift;
    {
        const int th = tbase - WAVE + lane;
        float h = (th >= 0) ? xr[th] : INIT_VAL;
        #pragma unroll
        for (int off = 1; off < WAVE; off <<= 1) {
            float t = __shfl_down(h, off, WAVE);
            h = (lane < WAVE - off) ? fminf(h, t) : h;
        }
        float s = __shfl_down(h, 1, WAVE);
        prevShift = (lane == WAVE - 1) ? INIT_VAL : s;
    }

    for (int s = 0; s < SEGS_PER_WAVE; ++s) {
        const int t0 = tbase + s * WAVE + lane;
        const float v = xr[t0];
        float P = v, S = v;
        #pragma unroll
        for (int off = 1; off < WAVE; off <<= 1) {
            float tu = __shfl_up(P, off, WAVE);
            P = (lane >= off) ? fminf(P, tu) : P;
            float td = __shfl_down(S, off, WAVE);
            S = (lane < WAVE - off) ? fminf(S, td) : S;
        }
        yr[t0] = fminf(P, prevShift);
        float sh = __shfl_down(S, 1, WAVE);
        prevShift = (lane == WAVE - 1) ? INIT_VAL : sh;
    }
}

extern "C" void kernel_launch(void* const* d_in, const int* in_sizes, int n_in,
                              void* d_out, int out_size, void* d_ws, size_t ws_size,
                              hipStream_t stream) {
    const float* x = (const float*)d_in[0];
    float* y = (float*)d_out;
    const int B = in_sizes[0] / T; // 4096 rows
    tlalw_kernel<<<B, WAVE * WAVES_PER_BLOCK, 0, stream>>>(x, y);
}

// Round 2
// 45.497 us; speedup vs baseline: 1.8366x; 1.8366x over previous
//
#include <hip/hip_runtime.h>

// Sliding-window min (window=64) over rows of T=8192 fp32, Gil-Werman with
// 4 elements/lane. Segment of 64 elements = 16 lanes x float4. Per iteration
// (256 elems/wave): lane-local prefix/suffix mins, exclusive prefix/suffix
// scans of lane aggregates within 16-lane groups (5+5 shuffles), segment
// shift (1 shuffle), rotate-by-16 to deliver prev-segment suffixes
// (4 shuffles). 15 wave-wide shuffles / 256 outputs -> DS pipe ~19us,
// below the ~43us HBM floor.

constexpr int T = 8192;
constexpr float INIT_VAL = 9999.0f;
constexpr int WAVE = 64;
constexpr int WAVES_PER_BLOCK = 4;
constexpr int CHUNK = WAVE * 4;                         // 256 elems/iter/wave
constexpr int ITERS = T / (WAVES_PER_BLOCK * CHUNK);    // 8

__global__ __launch_bounds__(WAVE * WAVES_PER_BLOCK)
void tlalw_kernel(const float* __restrict__ x, float* __restrict__ y) {
    const int lane = threadIdx.x & 63;
    const int g = lane & 15;                 // position within 16-lane group
    const int wv = threadIdx.x >> 6;
    const long long rowBase = (long long)blockIdx.x * T;
    const float* __restrict__ xr = x + rowBase;
    float* __restrict__ yr = y + rowBase;
    const int tbase = wv * (ITERS * CHUNK);
    const int rotIdx = (lane + 48) & 63;     // lane-16 mod 64

    // carry_j (valid in lanes 0..15): Sshift_j of the segment preceding this
    // iteration's segment 0.
    float carry0, carry1, carry2, carry3;

    // Prologue: halo segment [tbase-64, tbase). All four 16-lane groups
    // compute it redundantly; lanes 0..15 hold the carry.
    {
        float4 v;
        const int th = tbase - 64 + 4 * g;
        if (th >= 0) v = *(const float4*)(xr + th);
        else v = make_float4(INIT_VAL, INIT_VAL, INIT_VAL, INIT_VAL);
        float s3 = v.w, s2 = fminf(v.z, s3), s1 = fminf(v.y, s2), s0 = fminf(v.x, s1);
        float m = s0;
        float eS = __shfl_down(m, 1, 16); eS = (g == 15) ? INIT_VAL : eS;
        float t;
        t = __shfl_down(eS, 1, 16); if (g < 15) eS = fminf(eS, t);
        t = __shfl_down(eS, 2, 16); if (g < 14) eS = fminf(eS, t);
        t = __shfl_down(eS, 4, 16); if (g < 12) eS = fminf(eS, t);
        t = __shfl_down(eS, 8, 16); if (g < 8)  eS = fminf(eS, t);
        float S0 = fminf(eS, s0), S1 = fminf(eS, s1), S2 = fminf(eS, s2), S3 = fminf(eS, s3);
        float nS0 = __shfl_down(S0, 1, 16);
        carry0 = S1; carry1 = S2; carry2 = S3;
        carry3 = (g == 15) ? INIT_VAL : nS0;
    }

    #pragma unroll
    for (int it = 0; it < ITERS; ++it) {
        const int t0 = tbase + it * CHUNK + 4 * lane;
        float4 v = *(const float4*)(xr + t0);

        float p0 = v.x, p1 = fminf(p0, v.y), p2 = fminf(p1, v.z), p3 = fminf(p2, v.w);
        float s3 = v.w, s2 = fminf(v.z, s3), s1 = fminf(v.y, s2), s0 = fminf(v.x, s1);
        float m = p3;

        // exclusive prefix-min scan of m within 16-lane group
        float eP = __shfl_up(m, 1, 16); eP = (g == 0) ? INIT_VAL : eP;
        float t;
        t = __shfl_up(eP, 1, 16); if (g >= 1) eP = fminf(eP, t);
        t = __shfl_up(eP, 2, 16); if (g >= 2) eP = fminf(eP, t);
        t = __shfl_up(eP, 4, 16); if (g >= 4) eP = fminf(eP, t);
        t = __shfl_up(eP, 8, 16); if (g >= 8) eP = fminf(eP, t);

        // exclusive suffix-min scan of m within 16-lane group
        float eS = __shfl_down(m, 1, 16); eS = (g == 15) ? INIT_VAL : eS;
        t = __shfl_down(eS, 1, 16); if (g < 15) eS = fminf(eS, t);
        t = __shfl_down(eS, 2, 16); if (g < 14) eS = fminf(eS, t);
        t = __shfl_down(eS, 4, 16); if (g < 12) eS = fminf(eS, t);
        t = __shfl_down(eS, 8, 16); if (g < 8)  eS = fminf(eS, t);

        float P0 = fminf(eP, p0), P1 = fminf(eP, p1), P2 = fminf(eP, p2), P3 = fminf(eP, p3);
        float S0 = fminf(eS, s0), S1 = fminf(eS, s1), S2 = fminf(eS, s2), S3 = fminf(eS, s3);

        // Sshift_j = S[r+1] within segment; r+1==64 -> INIT
        float nS0 = __shfl_down(S0, 1, 16);
        float Sh0 = S1, Sh1 = S2, Sh2 = S3;
        float Sh3 = (g == 15) ? INIT_VAL : nS0;

        // rotate by 16 lanes: prev segment's Sshift (lanes>=16), and for
        // lanes 0..15 this delivers segment 3's Sshift = next iter's carry
        float r0 = __shfl(Sh0, rotIdx);
        float r1 = __shfl(Sh1, rotIdx);
        float r2 = __shfl(Sh2, rotIdx);
        float r3 = __shfl(Sh3, rotIdx);

        float pv0 = (lane >= 16) ? r0 : carry0;
        float pv1 = (lane >= 16) ? r1 : carry1;
        float pv2 = (lane >= 16) ? r2 : carry2;
        float pv3 = (lane >= 16) ? r3 : carry3;

        float4 o;
        o.x = fminf(P0, pv0);
        o.y = fminf(P1, pv1);
        o.z = fminf(P2, pv2);
        o.w = fminf(P3, pv3);
        *(float4*)(yr + t0) = o;

        carry0 = r0; carry1 = r1; carry2 = r2; carry3 = r3;
    }
}

extern "C" void kernel_launch(void* const* d_in, const int* in_sizes, int n_in,
                              void* d_out, int out_size, void* d_ws, size_t ws_size,
                              hipStream_t stream) {
    const float* x = (const float*)d_in[0];
    float* y = (float*)d_out;
    const int B = in_sizes[0] / T; // 4096 rows
    tlalw_kernel<<<B, WAVE * WAVES_PER_BLOCK, 0, stream>>>(x, y);
}